// Round 1
// baseline (515.723 us; speedup 1.0000x reference)
//
#include <hip/hip_runtime.h>

#define NB 4
#define NC 16
#define NP 76800
#define NK 100
#define NITER 10
#define BW2 0.0256f
#define TPB 256
#define PT 4
#define TILE (TPB*PT)      // 1024 points per block
#define NTILES (NP/TILE)   // 75

__global__ void ms_init(const float* __restrict__ feat, const int* __restrict__ seed,
                        float* __restrict__ means, float* __restrict__ gnum,
                        float* __restrict__ gden) {
    int t = blockIdx.x * blockDim.x + threadIdx.x;
    if (t >= NB * NK) return;
    int b = t / NK;
    long idx = (long)seed[t];
    for (int c = 0; c < NC; ++c)
        means[t * NC + c] = feat[((size_t)b * NC + c) * NP + idx];
    for (int c = 0; c < NC; ++c) gnum[t * NC + c] = 0.f;
    gden[t] = 0.f;
}

__global__ __launch_bounds__(TPB) void ms_accum(const float* __restrict__ feat,
                                                const float* __restrict__ means,
                                                float* __restrict__ gnum,
                                                float* __restrict__ gden) {
    __shared__ float sm[NK][NC];
    __shared__ float sm2[NK];
    __shared__ float snum[NK][NC];
    __shared__ float sden[NK];
    const int b = blockIdx.x / NTILES;
    const int tile = blockIdx.x % NTILES;
    const int tid = threadIdx.x;

    for (int i = tid; i < NK * NC; i += TPB) {
        (&sm[0][0])[i] = means[(size_t)b * NK * NC + i];
        (&snum[0][0])[i] = 0.f;
    }
    for (int i = tid; i < NK; i += TPB) sden[i] = 0.f;
    __syncthreads();
    if (tid < NK) {
        float s = 0.f;
        #pragma unroll
        for (int c = 0; c < NC; ++c) s += sm[tid][c] * sm[tid][c];
        sm2[tid] = s;
    }
    __syncthreads();

    float f[PT][NC];
    float f2[PT];
    #pragma unroll
    for (int c = 0; c < NC; ++c) {
        float4 v = reinterpret_cast<const float4*>(feat + ((size_t)b * NC + c) * NP)[tile * (TILE / 4) + tid];
        f[0][c] = v.x; f[1][c] = v.y; f[2][c] = v.z; f[3][c] = v.w;
    }
    #pragma unroll
    for (int j = 0; j < PT; ++j) {
        float s = 0.f;
        #pragma unroll
        for (int c = 0; c < NC; ++c) s += f[j][c] * f[j][c];
        f2[j] = s;
    }

    for (int k = 0; k < NK; ++k) {
        const float4* mk = reinterpret_cast<const float4*>(&sm[k][0]);
        float4 m0 = mk[0], m1 = mk[1], m2v = mk[2], m3 = mk[3];
        float mm[NC] = {m0.x, m0.y, m0.z, m0.w, m1.x, m1.y, m1.z, m1.w,
                        m2v.x, m2v.y, m2v.z, m2v.w, m3.x, m3.y, m3.z, m3.w};
        float m2 = sm2[k];
        #pragma unroll
        for (int j = 0; j < PT; ++j) {
            float dot = 0.f;
            #pragma unroll
            for (int c = 0; c < NC; ++c) dot = fmaf(f[j][c], mm[c], dot);
            float d2 = f2[j] - 2.f * dot + m2;
            if (d2 < BW2) {
                #pragma unroll
                for (int c = 0; c < NC; ++c) atomicAdd(&snum[k][c], f[j][c]);
                atomicAdd(&sden[k], 1.f);
            }
        }
    }
    __syncthreads();
    for (int i = tid; i < NK * NC; i += TPB) {
        float v = (&snum[0][0])[i];
        if (v != 0.f) atomicAdd(&gnum[(size_t)b * NK * NC + i], v);
    }
    for (int i = tid; i < NK; i += TPB) {
        float v = sden[i];
        if (v != 0.f) atomicAdd(&gden[(size_t)b * NK + i], v);
    }
}

__global__ void ms_update(float* __restrict__ means, float* __restrict__ gnum,
                          float* __restrict__ gden) {
    int t = blockIdx.x * blockDim.x + threadIdx.x;
    if (t >= NB * NK) return;
    float den = gden[t];
    for (int c = 0; c < NC; ++c) {
        float nm = gnum[t * NC + c];
        float old = means[t * NC + c];
        means[t * NC + c] = (den > 0.f) ? (nm / fmaxf(den, 1.f)) : old;
        gnum[t * NC + c] = 0.f;
    }
    gden[t] = 0.f;
}

__global__ __launch_bounds__(TPB) void ms_label(const float* __restrict__ feat,
                                                const float* __restrict__ means,
                                                float* __restrict__ out) {
    __shared__ float sm[NK][NC];
    __shared__ float sm2[NK];
    const int b = blockIdx.x / NTILES;
    const int tile = blockIdx.x % NTILES;
    const int tid = threadIdx.x;

    for (int i = tid; i < NK * NC; i += TPB)
        (&sm[0][0])[i] = means[(size_t)b * NK * NC + i];
    __syncthreads();
    if (tid < NK) {
        float s = 0.f;
        #pragma unroll
        for (int c = 0; c < NC; ++c) s += sm[tid][c] * sm[tid][c];
        sm2[tid] = s;
    }
    __syncthreads();

    float f[PT][NC];
    float f2[PT];
    #pragma unroll
    for (int c = 0; c < NC; ++c) {
        float4 v = reinterpret_cast<const float4*>(feat + ((size_t)b * NC + c) * NP)[tile * (TILE / 4) + tid];
        f[0][c] = v.x; f[1][c] = v.y; f[2][c] = v.z; f[3][c] = v.w;
    }
    #pragma unroll
    for (int j = 0; j < PT; ++j) {
        float s = 0.f;
        #pragma unroll
        for (int c = 0; c < NC; ++c) s += f[j][c] * f[j][c];
        f2[j] = s;
    }

    float best[PT];
    int bi[PT];
    #pragma unroll
    for (int j = 0; j < PT; ++j) { best[j] = 3.4e38f; bi[j] = 0; }

    for (int k = 0; k < NK; ++k) {
        const float4* mk = reinterpret_cast<const float4*>(&sm[k][0]);
        float4 m0 = mk[0], m1 = mk[1], m2v = mk[2], m3 = mk[3];
        float mm[NC] = {m0.x, m0.y, m0.z, m0.w, m1.x, m1.y, m1.z, m1.w,
                        m2v.x, m2v.y, m2v.z, m2v.w, m3.x, m3.y, m3.z, m3.w};
        float m2 = sm2[k];
        #pragma unroll
        for (int j = 0; j < PT; ++j) {
            float dot = 0.f;
            #pragma unroll
            for (int c = 0; c < NC; ++c) dot = fmaf(f[j][c], mm[c], dot);
            float d2 = f2[j] - 2.f * dot + m2;
            if (d2 < best[j]) { best[j] = d2; bi[j] = k; }
        }
    }

    float4 r;
    r.x = (best[0] < BW2) ? (float)(bi[0] + 1) : 0.f;
    r.y = (best[1] < BW2) ? (float)(bi[1] + 1) : 0.f;
    r.z = (best[2] < BW2) ? (float)(bi[2] + 1) : 0.f;
    r.w = (best[3] < BW2) ? (float)(bi[3] + 1) : 0.f;
    reinterpret_cast<float4*>(out + (size_t)b * NP)[tile * (TILE / 4) + tid] = r;
}

extern "C" void kernel_launch(void* const* d_in, const int* in_sizes, int n_in,
                              void* d_out, int out_size, void* d_ws, size_t ws_size,
                              hipStream_t stream) {
    const float* feat = (const float*)d_in[0];
    const int* seed = (const int*)d_in[1];
    float* out = (float*)d_out;

    float* means = (float*)d_ws;
    float* gnum = means + NB * NK * NC;
    float* gden = gnum + NB * NK * NC;

    ms_init<<<2, 256, 0, stream>>>(feat, seed, means, gnum, gden);
    for (int it = 0; it < NITER; ++it) {
        ms_accum<<<NB * NTILES, TPB, 0, stream>>>(feat, means, gnum, gden);
        ms_update<<<2, 256, 0, stream>>>(means, gnum, gden);
    }
    ms_label<<<NB * NTILES, TPB, 0, stream>>>(feat, means, out);
    hipMemcpyAsync(out + (size_t)NB * NP, means, NB * NK * NC * sizeof(float),
                   hipMemcpyDeviceToDevice, stream);
}

// Round 2
// 423.940 us; speedup vs baseline: 1.2165x; 1.2165x over previous
//
#include <hip/hip_runtime.h>

#define NB 4
#define NC 16
#define NP 76800
#define NK 100
#define NITER 10
#define BW2 0.0256f
#define TPB 256
#define TILEP 256
#define NTILES (NP/TILEP)   // 300
#define SSTR 20             // LDS floats per point: 16 feat + f2 + 3 pad (80B, 16B-aligned)

__global__ void ms_init(const float* __restrict__ feat, const int* __restrict__ seed,
                        float* __restrict__ means, float* __restrict__ gnum,
                        float* __restrict__ gden) {
    int t = blockIdx.x * blockDim.x + threadIdx.x;
    if (t >= NB * NK) return;
    int b = t / NK;
    long idx = (long)seed[t];
    for (int c = 0; c < NC; ++c)
        means[t * NC + c] = feat[((size_t)b * NC + c) * NP + idx];
    for (int c = 0; c < NC; ++c) gnum[t * NC + c] = 0.f;
    gden[t] = 0.f;
}

__global__ __launch_bounds__(TPB) void ms_accum(const float* __restrict__ feat,
                                                const float* __restrict__ means,
                                                float* __restrict__ gnum,
                                                float* __restrict__ gden) {
    __shared__ float sf[TILEP * SSTR];
    const int b = blockIdx.x / NTILES;
    const int tile = blockIdx.x % NTILES;
    const int tid = threadIdx.x;
    const int lane = tid & 63;
    const int w = tid >> 6;
    const int p0 = tile * TILEP;

    // stage: thread tid owns point p0+tid; global reads coalesced per c-row
    float fr[NC];
    #pragma unroll
    for (int c = 0; c < NC; ++c)
        fr[c] = feat[((size_t)b * NC + c) * NP + p0 + tid];
    float f2 = 0.f;
    #pragma unroll
    for (int c = 0; c < NC; ++c) f2 += fr[c] * fr[c];
    #pragma unroll
    for (int c = 0; c < NC; ++c) sf[tid * SSTR + c] = fr[c];
    sf[tid * SSTR + 16] = f2;
    __syncthreads();

    // lane-per-k: wave half (w&1) covers k = 0..63 or 64..127
    const int k = (w & 1) * 64 + lane;
    float mm[NC];
    float m2;
    if (k < NK) {
        const float4* mp = reinterpret_cast<const float4*>(means + ((size_t)b * NK + k) * NC);
        float4 a = mp[0], q = mp[1], r = mp[2], s = mp[3];
        mm[0]=a.x; mm[1]=a.y; mm[2]=a.z; mm[3]=a.w;
        mm[4]=q.x; mm[5]=q.y; mm[6]=q.z; mm[7]=q.w;
        mm[8]=r.x; mm[9]=r.y; mm[10]=r.z; mm[11]=r.w;
        mm[12]=s.x; mm[13]=s.y; mm[14]=s.z; mm[15]=s.w;
        m2 = 0.f;
        #pragma unroll
        for (int c = 0; c < NC; ++c) m2 += mm[c] * mm[c];
    } else {
        #pragma unroll
        for (int c = 0; c < NC; ++c) mm[c] = 0.f;
        m2 = 3.0e38f;  // d2 becomes huge -> never within bandwidth
    }

    float anum[NC];
    #pragma unroll
    for (int c = 0; c < NC; ++c) anum[c] = 0.f;
    float aden = 0.f;

    const int pbase = (w >> 1) * (TILEP / 2);
    #pragma unroll 2
    for (int i = 0; i < TILEP / 2; ++i) {
        const float* fp = &sf[(pbase + i) * SSTR];
        float4 v0 = *reinterpret_cast<const float4*>(fp);
        float4 v1 = *reinterpret_cast<const float4*>(fp + 4);
        float4 v2 = *reinterpret_cast<const float4*>(fp + 8);
        float4 v3 = *reinterpret_cast<const float4*>(fp + 12);
        float pf2 = fp[16];
        float ff[NC] = {v0.x, v0.y, v0.z, v0.w, v1.x, v1.y, v1.z, v1.w,
                        v2.x, v2.y, v2.z, v2.w, v3.x, v3.y, v3.z, v3.w};
        float dot = 0.f;
        #pragma unroll
        for (int c = 0; c < NC; ++c) dot = fmaf(ff[c], mm[c], dot);
        float d2 = (pf2 - 2.f * dot) + m2;
        if (__any(d2 < BW2)) {
            float sel = (d2 < BW2) ? 1.f : 0.f;
            #pragma unroll
            for (int c = 0; c < NC; ++c) anum[c] = fmaf(sel, ff[c], anum[c]);
            aden += sel;
        }
    }

    if (aden > 0.f) {  // k < NK guaranteed (invalid lanes never hit)
        float* gn = gnum + ((size_t)b * NK + k) * NC;
        #pragma unroll
        for (int c = 0; c < NC; ++c) atomicAdd(&gn[c], anum[c]);
        atomicAdd(&gden[(size_t)b * NK + k], aden);
    }
}

__global__ void ms_update(float* __restrict__ means, float* __restrict__ gnum,
                          float* __restrict__ gden) {
    int t = blockIdx.x * blockDim.x + threadIdx.x;
    if (t >= NB * NK) return;
    float den = gden[t];
    for (int c = 0; c < NC; ++c) {
        float nm = gnum[t * NC + c];
        float old = means[t * NC + c];
        means[t * NC + c] = (den > 0.f) ? (nm / fmaxf(den, 1.f)) : old;
        gnum[t * NC + c] = 0.f;
    }
    gden[t] = 0.f;
}

__global__ __launch_bounds__(TPB) void ms_label(const float* __restrict__ feat,
                                                const float* __restrict__ means,
                                                float* __restrict__ out) {
    __shared__ float sf[TILEP * SSTR];
    const int b = blockIdx.x / NTILES;
    const int tile = blockIdx.x % NTILES;
    const int tid = threadIdx.x;
    const int lane = tid & 63;
    const int w = tid >> 6;
    const int p0 = tile * TILEP;

    float fr[NC];
    #pragma unroll
    for (int c = 0; c < NC; ++c)
        fr[c] = feat[((size_t)b * NC + c) * NP + p0 + tid];
    float f2 = 0.f;
    #pragma unroll
    for (int c = 0; c < NC; ++c) f2 += fr[c] * fr[c];
    #pragma unroll
    for (int c = 0; c < NC; ++c) sf[tid * SSTR + c] = fr[c];
    sf[tid * SSTR + 16] = f2;
    __syncthreads();

    // each lane holds two k's: k0 = lane (<100 always), k1 = 64+lane (valid if <100)
    const int k0 = lane;
    const int k1 = 64 + lane;
    float mA[NC], mB[NC];
    float m2A, m2B;
    {
        const float4* mp = reinterpret_cast<const float4*>(means + ((size_t)b * NK + k0) * NC);
        float4 a = mp[0], q = mp[1], r = mp[2], s = mp[3];
        mA[0]=a.x; mA[1]=a.y; mA[2]=a.z; mA[3]=a.w;
        mA[4]=q.x; mA[5]=q.y; mA[6]=q.z; mA[7]=q.w;
        mA[8]=r.x; mA[9]=r.y; mA[10]=r.z; mA[11]=r.w;
        mA[12]=s.x; mA[13]=s.y; mA[14]=s.z; mA[15]=s.w;
        m2A = 0.f;
        #pragma unroll
        for (int c = 0; c < NC; ++c) m2A += mA[c] * mA[c];
    }
    if (k1 < NK) {
        const float4* mp = reinterpret_cast<const float4*>(means + ((size_t)b * NK + k1) * NC);
        float4 a = mp[0], q = mp[1], r = mp[2], s = mp[3];
        mB[0]=a.x; mB[1]=a.y; mB[2]=a.z; mB[3]=a.w;
        mB[4]=q.x; mB[5]=q.y; mB[6]=q.z; mB[7]=q.w;
        mB[8]=r.x; mB[9]=r.y; mB[10]=r.z; mB[11]=r.w;
        mB[12]=s.x; mB[13]=s.y; mB[14]=s.z; mB[15]=s.w;
        m2B = 0.f;
        #pragma unroll
        for (int c = 0; c < NC; ++c) m2B += mB[c] * mB[c];
    } else {
        #pragma unroll
        for (int c = 0; c < NC; ++c) mB[c] = 0.f;
        m2B = 3.0e38f;
    }

    const int pbase = w * 64;  // each wave labels 64 points over all k
    float myval = 0.f;
    for (int i = 0; i < 64; ++i) {
        const float* fp = &sf[(pbase + i) * SSTR];
        float4 v0 = *reinterpret_cast<const float4*>(fp);
        float4 v1 = *reinterpret_cast<const float4*>(fp + 4);
        float4 v2 = *reinterpret_cast<const float4*>(fp + 8);
        float4 v3 = *reinterpret_cast<const float4*>(fp + 12);
        float pf2 = fp[16];
        float ff[NC] = {v0.x, v0.y, v0.z, v0.w, v1.x, v1.y, v1.z, v1.w,
                        v2.x, v2.y, v2.z, v2.w, v3.x, v3.y, v3.z, v3.w};
        float dotA = 0.f, dotB = 0.f;
        #pragma unroll
        for (int c = 0; c < NC; ++c) dotA = fmaf(ff[c], mA[c], dotA);
        #pragma unroll
        for (int c = 0; c < NC; ++c) dotB = fmaf(ff[c], mB[c], dotB);
        float d2A = (pf2 - 2.f * dotA) + m2A;
        float d2B = (pf2 - 2.f * dotB) + m2B;
        float d2 = d2A;
        int kk = k0;
        if (d2B < d2) { d2 = d2B; kk = k1; }  // tie keeps k0 (smaller)
        #pragma unroll
        for (int off = 32; off; off >>= 1) {
            float od2 = __shfl_xor(d2, off);
            int ok = __shfl_xor(kk, off);
            if (od2 < d2 || (od2 == d2 && ok < kk)) { d2 = od2; kk = ok; }
        }
        float lab = (d2 < BW2) ? (float)(kk + 1) : 0.f;
        if (lane == i) myval = lab;
    }
    out[(size_t)b * NP + p0 + pbase + lane] = myval;
}

extern "C" void kernel_launch(void* const* d_in, const int* in_sizes, int n_in,
                              void* d_out, int out_size, void* d_ws, size_t ws_size,
                              hipStream_t stream) {
    const float* feat = (const float*)d_in[0];
    const int* seed = (const int*)d_in[1];
    float* out = (float*)d_out;

    float* means = (float*)d_ws;
    float* gnum = means + NB * NK * NC;
    float* gden = gnum + NB * NK * NC;

    ms_init<<<2, 256, 0, stream>>>(feat, seed, means, gnum, gden);
    for (int it = 0; it < NITER; ++it) {
        ms_accum<<<NB * NTILES, TPB, 0, stream>>>(feat, means, gnum, gden);
        ms_update<<<2, 256, 0, stream>>>(means, gnum, gden);
    }
    ms_label<<<NB * NTILES, TPB, 0, stream>>>(feat, means, out);
    hipMemcpyAsync(out + (size_t)NB * NP, means, NB * NK * NC * sizeof(float),
                   hipMemcpyDeviceToDevice, stream);
}

// Round 3
// 304.074 us; speedup vs baseline: 1.6960x; 1.3942x over previous
//
#include <hip/hip_runtime.h>

#define NB 4
#define NC 16
#define NP 76800
#define NK 100
#define NITER 10
#define BW2 0.0256f
#define TPB 256
#define PT 4
#define TILEP (TPB*PT)        // 1024 points per block
#define NTILES (NP/TILEP)     // 75
#define KS 2                  // k-split
#define KPB (NK/KS)           // 50

// ws layout (floats): means2[2][NB*NK*NC] | gnum3[3][NB*NK*NC] | gden3[3][NB*NK]
#define MEANS_OFF 0
#define GNUM_OFF  (2*NB*NK*NC)
#define GDEN_OFF  (GNUM_OFF + 3*NB*NK*NC)

__global__ void ms_init(const float* __restrict__ feat, const int* __restrict__ seed,
                        float* __restrict__ ws) {
    int t = blockIdx.x * blockDim.x + threadIdx.x;
    int stride = gridDim.x * blockDim.x;
    // zero gnum3 + gden3 (contiguous)
    for (int i = t; i < 3 * NB * NK * NC + 3 * NB * NK; i += stride)
        ws[GNUM_OFF + i] = 0.f;
    // gather initial means into means buffer 1  (acts as means_{-1})
    if (t < NB * NK) {
        int b = t / NK;
        int idx = seed[t];
        float* m = ws + MEANS_OFF + NB * NK * NC + t * NC;
        for (int c = 0; c < NC; ++c)
            m[c] = feat[((size_t)b * NC + c) * NP + idx];
    }
}

// means_i = update(gnum_{i-1}, gden_{i-1}, means_{i-1}) computed per block in prologue.
__global__ __launch_bounds__(TPB) void ms_accum(const float* __restrict__ feat,
                                                float* __restrict__ ws,
                                                int rIdx, int aIdx, int zIdx,
                                                int prevM, int curM) {
    __shared__ float sm[NK][NC];
    __shared__ float sm2[NK];
    __shared__ float snum[KPB][NC];
    __shared__ float sden[KPB];
    const int bid = blockIdx.x;
    const int ks = bid & 1;
    const int t2 = bid >> 1;
    const int b = t2 / NTILES;
    const int tile = t2 % NTILES;
    const int tid = threadIdx.x;

    float* gnumR = ws + GNUM_OFF + (size_t)rIdx * NB * NK * NC + (size_t)b * NK * NC;
    float* gnumA = ws + GNUM_OFF + (size_t)aIdx * NB * NK * NC + (size_t)b * NK * NC;
    float* gnumZ = ws + GNUM_OFF + (size_t)zIdx * NB * NK * NC + (size_t)b * NK * NC;
    float* gdenR = ws + GDEN_OFF + rIdx * NB * NK + b * NK;
    float* gdenA = ws + GDEN_OFF + aIdx * NB * NK + b * NK;
    float* gdenZ = ws + GDEN_OFF + zIdx * NB * NK + b * NK;
    float* mPrev = ws + MEANS_OFF + (size_t)prevM * NB * NK * NC + (size_t)b * NK * NC;
    float* mCur  = ws + MEANS_OFF + (size_t)curM  * NB * NK * NC + (size_t)b * NK * NC;

    // ---- prologue: every block computes all 100 new means into LDS ----
    if (tid < NK) {
        const int k = tid;
        float den = gdenR[k];
        const float4* gn4 = reinterpret_cast<const float4*>(gnumR + k * NC);
        const float4* mp4 = reinterpret_cast<const float4*>(mPrev + k * NC);
        float4 g0 = gn4[0], g1 = gn4[1], g2 = gn4[2], g3 = gn4[3];
        float4 o0 = mp4[0], o1 = mp4[1], o2 = mp4[2], o3 = mp4[3];
        float gg[NC] = {g0.x,g0.y,g0.z,g0.w, g1.x,g1.y,g1.z,g1.w,
                        g2.x,g2.y,g2.z,g2.w, g3.x,g3.y,g3.z,g3.w};
        float oo[NC] = {o0.x,o0.y,o0.z,o0.w, o1.x,o1.y,o1.z,o1.w,
                        o2.x,o2.y,o2.z,o2.w, o3.x,o3.y,o3.z,o3.w};
        float inv = fmaxf(den, 1.f);
        bool pos = den > 0.f;
        float nm[NC];
        #pragma unroll
        for (int c = 0; c < NC; ++c) nm[c] = pos ? (gg[c] / inv) : oo[c];
        #pragma unroll
        for (int c = 0; c < NC; ++c) sm[k][c] = nm[c];
        float s = 0.f;
        #pragma unroll
        for (int c = 0; c < NC; ++c) s += nm[c] * nm[c];
        sm2[k] = s;
        if (ks == 0 && tile == 0) {  // persist means_i for next dispatch
            float4* mc4 = reinterpret_cast<float4*>(mCur + k * NC);
            mc4[0] = make_float4(nm[0], nm[1], nm[2], nm[3]);
            mc4[1] = make_float4(nm[4], nm[5], nm[6], nm[7]);
            mc4[2] = make_float4(nm[8], nm[9], nm[10], nm[11]);
            mc4[3] = make_float4(nm[12], nm[13], nm[14], nm[15]);
        }
    }
    for (int i = tid; i < KPB * NC; i += TPB) (&snum[0][0])[i] = 0.f;
    if (tid < KPB) sden[tid] = 0.f;
    if (ks == 1 && tile == 0) {  // zero next iteration's accumulation buffer
        for (int i = tid; i < NK * NC; i += TPB) gnumZ[i] = 0.f;
        if (tid < NK) gdenZ[tid] = 0.f;
    }

    // ---- load 4 points into registers (float4 per c, fully coalesced) ----
    const int p0 = tile * TILEP + tid * PT;
    float fA[NC], fB[NC], fC[NC], fD[NC];
    #pragma unroll
    for (int c = 0; c < NC; ++c) {
        float4 v = *reinterpret_cast<const float4*>(feat + ((size_t)b * NC + c) * NP + p0);
        fA[c] = v.x; fB[c] = v.y; fC[c] = v.z; fD[c] = v.w;
    }
    float f2A = 0.f, f2B = 0.f, f2C = 0.f, f2D = 0.f;
    #pragma unroll
    for (int c = 0; c < NC; ++c) f2A += fA[c] * fA[c];
    #pragma unroll
    for (int c = 0; c < NC; ++c) f2B += fB[c] * fB[c];
    #pragma unroll
    for (int c = 0; c < NC; ++c) f2C += fC[c] * fC[c];
    #pragma unroll
    for (int c = 0; c < NC; ++c) f2D += fD[c] * fD[c];
    __syncthreads();

    // ---- hot loop: 50 k's, broadcast LDS means, 4-way ILP FMA chains ----
    const float4* smv = reinterpret_cast<const float4*>(&sm[0][0]);
    const int kbeg = ks * KPB;
    #pragma unroll 2
    for (int k = kbeg; k < kbeg + KPB; ++k) {
        float4 m0 = smv[k * 4 + 0], m1 = smv[k * 4 + 1];
        float4 m2v = smv[k * 4 + 2], m3 = smv[k * 4 + 3];
        float mm[NC] = {m0.x,m0.y,m0.z,m0.w, m1.x,m1.y,m1.z,m1.w,
                        m2v.x,m2v.y,m2v.z,m2v.w, m3.x,m3.y,m3.z,m3.w};
        float m2 = sm2[k];
        float dA = 0.f, dB = 0.f, dC = 0.f, dD = 0.f;
        #pragma unroll
        for (int c = 0; c < NC; ++c) {
            float mc = mm[c];
            dA = fmaf(fA[c], mc, dA);
            dB = fmaf(fB[c], mc, dB);
            dC = fmaf(fC[c], mc, dC);
            dD = fmaf(fD[c], mc, dD);
        }
        float d2A = (f2A - 2.f * dA) + m2;
        float d2B = (f2B - 2.f * dB) + m2;
        float d2C = (f2C - 2.f * dC) + m2;
        float d2D = (f2D - 2.f * dD) + m2;
        bool hA = d2A < BW2, hB = d2B < BW2, hC = d2C < BW2, hD = d2D < BW2;
        if (__any(hA | hB | hC | hD)) {  // rare
            int kk = k - kbeg;
            if (hA) {
                #pragma unroll
                for (int c = 0; c < NC; ++c) atomicAdd(&snum[kk][c], fA[c]);
                atomicAdd(&sden[kk], 1.f);
            }
            if (hB) {
                #pragma unroll
                for (int c = 0; c < NC; ++c) atomicAdd(&snum[kk][c], fB[c]);
                atomicAdd(&sden[kk], 1.f);
            }
            if (hC) {
                #pragma unroll
                for (int c = 0; c < NC; ++c) atomicAdd(&snum[kk][c], fC[c]);
                atomicAdd(&sden[kk], 1.f);
            }
            if (hD) {
                #pragma unroll
                for (int c = 0; c < NC; ++c) atomicAdd(&snum[kk][c], fD[c]);
                atomicAdd(&sden[kk], 1.f);
            }
        }
    }

    // ---- flush block-local sums (only nonzero entries; usually none) ----
    __syncthreads();
    for (int i = tid; i < KPB * NC; i += TPB) {
        float v = (&snum[0][0])[i];
        if (v != 0.f) atomicAdd(&gnumA[kbeg * NC + i], v);
    }
    if (tid < KPB) {
        float v = sden[tid];
        if (v != 0.f) atomicAdd(&gdenA[kbeg + tid], v);
    }
}

__global__ __launch_bounds__(TPB) void ms_label(const float* __restrict__ feat,
                                                float* __restrict__ ws,
                                                float* __restrict__ out,
                                                int rIdx, int prevM) {
    __shared__ float sm[NK][NC];
    __shared__ float sm2[NK];
    const int b = blockIdx.x / NTILES;
    const int tile = blockIdx.x % NTILES;
    const int tid = threadIdx.x;

    float* gnumR = ws + GNUM_OFF + (size_t)rIdx * NB * NK * NC + (size_t)b * NK * NC;
    float* gdenR = ws + GDEN_OFF + rIdx * NB * NK + b * NK;
    float* mPrev = ws + MEANS_OFF + (size_t)prevM * NB * NK * NC + (size_t)b * NK * NC;

    if (tid < NK) {
        const int k = tid;
        float den = gdenR[k];
        const float4* gn4 = reinterpret_cast<const float4*>(gnumR + k * NC);
        const float4* mp4 = reinterpret_cast<const float4*>(mPrev + k * NC);
        float4 g0 = gn4[0], g1 = gn4[1], g2 = gn4[2], g3 = gn4[3];
        float4 o0 = mp4[0], o1 = mp4[1], o2 = mp4[2], o3 = mp4[3];
        float gg[NC] = {g0.x,g0.y,g0.z,g0.w, g1.x,g1.y,g1.z,g1.w,
                        g2.x,g2.y,g2.z,g2.w, g3.x,g3.y,g3.z,g3.w};
        float oo[NC] = {o0.x,o0.y,o0.z,o0.w, o1.x,o1.y,o1.z,o1.w,
                        o2.x,o2.y,o2.z,o2.w, o3.x,o3.y,o3.z,o3.w};
        float inv = fmaxf(den, 1.f);
        bool pos = den > 0.f;
        float nm[NC];
        #pragma unroll
        for (int c = 0; c < NC; ++c) nm[c] = pos ? (gg[c] / inv) : oo[c];
        #pragma unroll
        for (int c = 0; c < NC; ++c) sm[k][c] = nm[c];
        float s = 0.f;
        #pragma unroll
        for (int c = 0; c < NC; ++c) s += nm[c] * nm[c];
        sm2[k] = s;
        if (tile == 0) {  // final means -> output tail
            float* mo = out + (size_t)NB * NP + (size_t)b * NK * NC + k * NC;
            float4* mo4 = reinterpret_cast<float4*>(mo);
            mo4[0] = make_float4(nm[0], nm[1], nm[2], nm[3]);
            mo4[1] = make_float4(nm[4], nm[5], nm[6], nm[7]);
            mo4[2] = make_float4(nm[8], nm[9], nm[10], nm[11]);
            mo4[3] = make_float4(nm[12], nm[13], nm[14], nm[15]);
        }
    }

    const int p0 = tile * TILEP + tid * PT;
    float fA[NC], fB[NC], fC[NC], fD[NC];
    #pragma unroll
    for (int c = 0; c < NC; ++c) {
        float4 v = *reinterpret_cast<const float4*>(feat + ((size_t)b * NC + c) * NP + p0);
        fA[c] = v.x; fB[c] = v.y; fC[c] = v.z; fD[c] = v.w;
    }
    float f2A = 0.f, f2B = 0.f, f2C = 0.f, f2D = 0.f;
    #pragma unroll
    for (int c = 0; c < NC; ++c) f2A += fA[c] * fA[c];
    #pragma unroll
    for (int c = 0; c < NC; ++c) f2B += fB[c] * fB[c];
    #pragma unroll
    for (int c = 0; c < NC; ++c) f2C += fC[c] * fC[c];
    #pragma unroll
    for (int c = 0; c < NC; ++c) f2D += fD[c] * fD[c];
    __syncthreads();

    float bestA = 3.4e38f, bestB = 3.4e38f, bestC = 3.4e38f, bestD = 3.4e38f;
    int biA = 0, biB = 0, biC = 0, biD = 0;
    const float4* smv = reinterpret_cast<const float4*>(&sm[0][0]);
    #pragma unroll 2
    for (int k = 0; k < NK; ++k) {
        float4 m0 = smv[k * 4 + 0], m1 = smv[k * 4 + 1];
        float4 m2v = smv[k * 4 + 2], m3 = smv[k * 4 + 3];
        float mm[NC] = {m0.x,m0.y,m0.z,m0.w, m1.x,m1.y,m1.z,m1.w,
                        m2v.x,m2v.y,m2v.z,m2v.w, m3.x,m3.y,m3.z,m3.w};
        float m2 = sm2[k];
        float dA = 0.f, dB = 0.f, dC = 0.f, dD = 0.f;
        #pragma unroll
        for (int c = 0; c < NC; ++c) {
            float mc = mm[c];
            dA = fmaf(fA[c], mc, dA);
            dB = fmaf(fB[c], mc, dB);
            dC = fmaf(fC[c], mc, dC);
            dD = fmaf(fD[c], mc, dD);
        }
        float d2A = (f2A - 2.f * dA) + m2;
        float d2B = (f2B - 2.f * dB) + m2;
        float d2C = (f2C - 2.f * dC) + m2;
        float d2D = (f2D - 2.f * dD) + m2;
        if (d2A < bestA) { bestA = d2A; biA = k; }
        if (d2B < bestB) { bestB = d2B; biB = k; }
        if (d2C < bestC) { bestC = d2C; biC = k; }
        if (d2D < bestD) { bestD = d2D; biD = k; }
    }

    float4 r;
    r.x = (bestA < BW2) ? (float)(biA + 1) : 0.f;
    r.y = (bestB < BW2) ? (float)(biB + 1) : 0.f;
    r.z = (bestC < BW2) ? (float)(biC + 1) : 0.f;
    r.w = (bestD < BW2) ? (float)(biD + 1) : 0.f;
    *reinterpret_cast<float4*>(out + (size_t)b * NP + p0) = r;
}

extern "C" void kernel_launch(void* const* d_in, const int* in_sizes, int n_in,
                              void* d_out, int out_size, void* d_ws, size_t ws_size,
                              hipStream_t stream) {
    const float* feat = (const float*)d_in[0];
    const int* seed = (const int*)d_in[1];
    float* out = (float*)d_out;
    float* ws = (float*)d_ws;

    ms_init<<<84, 256, 0, stream>>>(feat, seed, ws);
    for (int i = 0; i < NITER; ++i) {
        ms_accum<<<NB * NTILES * KS, TPB, 0, stream>>>(
            feat, ws, (i + 2) % 3, i % 3, (i + 1) % 3, (i + 1) & 1, i & 1);
    }
    ms_label<<<NB * NTILES, TPB, 0, stream>>>(feat, ws, out, (NITER + 2) % 3, (NITER + 1) & 1);
}

// Round 4
// 303.384 us; speedup vs baseline: 1.6999x; 1.0023x over previous
//
#include <hip/hip_runtime.h>

#define NB 4
#define NC 16
#define NP 76800
#define NK 100
#define NITER 10
#define BW2 0.0256f
#define TPB 256
#define PT 4
#define TILEP (TPB*PT)        // 1024 points per accum block
#define NTILES (NP/TILEP)     // 75
#define KS 4                  // k-split
#define KPB (NK/KS)           // 25
// label: 1 point/thread
#define LTILEP TPB            // 256
#define LNTILES (NP/LTILEP)   // 300

// ws layout (floats): means2[2][NB*NK*NC] | gnum3[3][NB*NK*NC] | gden3[3][NB*NK]
#define MEANS_OFF 0
#define GNUM_OFF  (2*NB*NK*NC)
#define GDEN_OFF  (GNUM_OFF + 3*NB*NK*NC)

__global__ void ms_init(const float* __restrict__ feat, const int* __restrict__ seed,
                        float* __restrict__ ws) {
    int t = blockIdx.x * blockDim.x + threadIdx.x;
    int stride = gridDim.x * blockDim.x;
    for (int i = t; i < 3 * NB * NK * NC + 3 * NB * NK; i += stride)
        ws[GNUM_OFF + i] = 0.f;
    if (t < NB * NK) {
        int b = t / NK;
        int idx = seed[t];
        float* m = ws + MEANS_OFF + NB * NK * NC + t * NC;
        for (int c = 0; c < NC; ++c)
            m[c] = feat[((size_t)b * NC + c) * NP + idx];
    }
}

// means_i = update(gnum_{i-1}, gden_{i-1}, means_{i-1}) computed per block in prologue.
__global__ __launch_bounds__(TPB, 4) void ms_accum(const float* __restrict__ feat,
                                                   float* __restrict__ ws,
                                                   int rIdx, int aIdx, int zIdx,
                                                   int prevM, int curM) {
    __shared__ float sm[NK][NC];
    __shared__ float sm2[NK];
    __shared__ float snum[KPB][NC];
    __shared__ float sden[KPB];
    const int bid = blockIdx.x;
    const int ks = bid & (KS - 1);
    const int t2 = bid >> 2;
    const int b = t2 / NTILES;
    const int tile = t2 % NTILES;
    const int tid = threadIdx.x;

    float* gnumR = ws + GNUM_OFF + (size_t)rIdx * NB * NK * NC + (size_t)b * NK * NC;
    float* gnumA = ws + GNUM_OFF + (size_t)aIdx * NB * NK * NC + (size_t)b * NK * NC;
    float* gnumZ = ws + GNUM_OFF + (size_t)zIdx * NB * NK * NC + (size_t)b * NK * NC;
    float* gdenR = ws + GDEN_OFF + rIdx * NB * NK + b * NK;
    float* gdenA = ws + GDEN_OFF + aIdx * NB * NK + b * NK;
    float* gdenZ = ws + GDEN_OFF + zIdx * NB * NK + b * NK;
    float* mPrev = ws + MEANS_OFF + (size_t)prevM * NB * NK * NC + (size_t)b * NK * NC;
    float* mCur  = ws + MEANS_OFF + (size_t)curM  * NB * NK * NC + (size_t)b * NK * NC;

    // ---- prologue: every block computes all 100 new means into LDS ----
    if (tid < NK) {
        const int k = tid;
        float den = gdenR[k];
        const float4* gn4 = reinterpret_cast<const float4*>(gnumR + k * NC);
        const float4* mp4 = reinterpret_cast<const float4*>(mPrev + k * NC);
        float4 g0 = gn4[0], g1 = gn4[1], g2 = gn4[2], g3 = gn4[3];
        float4 o0 = mp4[0], o1 = mp4[1], o2 = mp4[2], o3 = mp4[3];
        float gg[NC] = {g0.x,g0.y,g0.z,g0.w, g1.x,g1.y,g1.z,g1.w,
                        g2.x,g2.y,g2.z,g2.w, g3.x,g3.y,g3.z,g3.w};
        float oo[NC] = {o0.x,o0.y,o0.z,o0.w, o1.x,o1.y,o1.z,o1.w,
                        o2.x,o2.y,o2.z,o2.w, o3.x,o3.y,o3.z,o3.w};
        float inv = fmaxf(den, 1.f);
        bool pos = den > 0.f;
        float nm[NC];
        #pragma unroll
        for (int c = 0; c < NC; ++c) nm[c] = pos ? (gg[c] / inv) : oo[c];
        #pragma unroll
        for (int c = 0; c < NC; ++c) sm[k][c] = nm[c];
        float s = 0.f;
        #pragma unroll
        for (int c = 0; c < NC; ++c) s += nm[c] * nm[c];
        sm2[k] = s;
        if (ks == 0 && tile == 0) {  // persist means_i for next dispatch
            float4* mc4 = reinterpret_cast<float4*>(mCur + k * NC);
            mc4[0] = make_float4(nm[0], nm[1], nm[2], nm[3]);
            mc4[1] = make_float4(nm[4], nm[5], nm[6], nm[7]);
            mc4[2] = make_float4(nm[8], nm[9], nm[10], nm[11]);
            mc4[3] = make_float4(nm[12], nm[13], nm[14], nm[15]);
        }
    }
    for (int i = tid; i < KPB * NC; i += TPB) (&snum[0][0])[i] = 0.f;
    if (tid < KPB) sden[tid] = 0.f;
    if (ks == 1 && tile == 0) {  // zero next iteration's accumulation buffer
        for (int i = tid; i < NK * NC; i += TPB) gnumZ[i] = 0.f;
        if (tid < NK) gdenZ[tid] = 0.f;
    }

    // ---- load 4 points into registers (float4 per c, fully coalesced) ----
    const int p0 = tile * TILEP + tid * PT;
    float fA[NC], fB[NC], fC[NC], fD[NC];
    #pragma unroll
    for (int c = 0; c < NC; ++c) {
        float4 v = *reinterpret_cast<const float4*>(feat + ((size_t)b * NC + c) * NP + p0);
        fA[c] = v.x; fB[c] = v.y; fC[c] = v.z; fD[c] = v.w;
    }
    float f2A = 0.f, f2B = 0.f, f2C = 0.f, f2D = 0.f;
    #pragma unroll
    for (int c = 0; c < NC; ++c) f2A += fA[c] * fA[c];
    #pragma unroll
    for (int c = 0; c < NC; ++c) f2B += fB[c] * fB[c];
    #pragma unroll
    for (int c = 0; c < NC; ++c) f2C += fC[c] * fC[c];
    #pragma unroll
    for (int c = 0; c < NC; ++c) f2D += fD[c] * fD[c];
    __syncthreads();

    // ---- hot loop: KPB k's, broadcast LDS means, 4-way ILP FMA chains ----
    const float4* smv = reinterpret_cast<const float4*>(&sm[0][0]);
    const int kbeg = ks * KPB;
    #pragma unroll 2
    for (int k = kbeg; k < kbeg + KPB; ++k) {
        float4 m0 = smv[k * 4 + 0], m1 = smv[k * 4 + 1];
        float4 m2v = smv[k * 4 + 2], m3 = smv[k * 4 + 3];
        float mm[NC] = {m0.x,m0.y,m0.z,m0.w, m1.x,m1.y,m1.z,m1.w,
                        m2v.x,m2v.y,m2v.z,m2v.w, m3.x,m3.y,m3.z,m3.w};
        float m2 = sm2[k];
        float dA = 0.f, dB = 0.f, dC = 0.f, dD = 0.f;
        #pragma unroll
        for (int c = 0; c < NC; ++c) {
            float mc = mm[c];
            dA = fmaf(fA[c], mc, dA);
            dB = fmaf(fB[c], mc, dB);
            dC = fmaf(fC[c], mc, dC);
            dD = fmaf(fD[c], mc, dD);
        }
        float d2A = (f2A - 2.f * dA) + m2;
        float d2B = (f2B - 2.f * dB) + m2;
        float d2C = (f2C - 2.f * dC) + m2;
        float d2D = (f2D - 2.f * dD) + m2;
        bool hA = d2A < BW2, hB = d2B < BW2, hC = d2C < BW2, hD = d2D < BW2;
        if (__any(hA | hB | hC | hD)) {  // rare
            int kk = k - kbeg;
            if (hA) {
                #pragma unroll
                for (int c = 0; c < NC; ++c) atomicAdd(&snum[kk][c], fA[c]);
                atomicAdd(&sden[kk], 1.f);
            }
            if (hB) {
                #pragma unroll
                for (int c = 0; c < NC; ++c) atomicAdd(&snum[kk][c], fB[c]);
                atomicAdd(&sden[kk], 1.f);
            }
            if (hC) {
                #pragma unroll
                for (int c = 0; c < NC; ++c) atomicAdd(&snum[kk][c], fC[c]);
                atomicAdd(&sden[kk], 1.f);
            }
            if (hD) {
                #pragma unroll
                for (int c = 0; c < NC; ++c) atomicAdd(&snum[kk][c], fD[c]);
                atomicAdd(&sden[kk], 1.f);
            }
        }
    }

    // ---- flush block-local sums (only nonzero entries; usually none) ----
    __syncthreads();
    for (int i = tid; i < KPB * NC; i += TPB) {
        float v = (&snum[0][0])[i];
        if (v != 0.f) atomicAdd(&gnumA[kbeg * NC + i], v);
    }
    if (tid < KPB) {
        float v = sden[tid];
        if (v != 0.f) atomicAdd(&gdenA[kbeg + tid], v);
    }
}

__global__ __launch_bounds__(TPB, 4) void ms_label(const float* __restrict__ feat,
                                                   float* __restrict__ ws,
                                                   float* __restrict__ out,
                                                   int rIdx, int prevM) {
    __shared__ float sm[NK][NC];
    __shared__ float sm2[NK];
    const int b = blockIdx.x / LNTILES;
    const int tile = blockIdx.x % LNTILES;
    const int tid = threadIdx.x;

    float* gnumR = ws + GNUM_OFF + (size_t)rIdx * NB * NK * NC + (size_t)b * NK * NC;
    float* gdenR = ws + GDEN_OFF + rIdx * NB * NK + b * NK;
    float* mPrev = ws + MEANS_OFF + (size_t)prevM * NB * NK * NC + (size_t)b * NK * NC;

    if (tid < NK) {
        const int k = tid;
        float den = gdenR[k];
        const float4* gn4 = reinterpret_cast<const float4*>(gnumR + k * NC);
        const float4* mp4 = reinterpret_cast<const float4*>(mPrev + k * NC);
        float4 g0 = gn4[0], g1 = gn4[1], g2 = gn4[2], g3 = gn4[3];
        float4 o0 = mp4[0], o1 = mp4[1], o2 = mp4[2], o3 = mp4[3];
        float gg[NC] = {g0.x,g0.y,g0.z,g0.w, g1.x,g1.y,g1.z,g1.w,
                        g2.x,g2.y,g2.z,g2.w, g3.x,g3.y,g3.z,g3.w};
        float oo[NC] = {o0.x,o0.y,o0.z,o0.w, o1.x,o1.y,o1.z,o1.w,
                        o2.x,o2.y,o2.z,o2.w, o3.x,o3.y,o3.z,o3.w};
        float inv = fmaxf(den, 1.f);
        bool pos = den > 0.f;
        float nm[NC];
        #pragma unroll
        for (int c = 0; c < NC; ++c) nm[c] = pos ? (gg[c] / inv) : oo[c];
        #pragma unroll
        for (int c = 0; c < NC; ++c) sm[k][c] = nm[c];
        float s = 0.f;
        #pragma unroll
        for (int c = 0; c < NC; ++c) s += nm[c] * nm[c];
        sm2[k] = s;
        if (tile == 0) {  // final means -> output tail
            float* mo = out + (size_t)NB * NP + (size_t)b * NK * NC + k * NC;
            float4* mo4 = reinterpret_cast<float4*>(mo);
            mo4[0] = make_float4(nm[0], nm[1], nm[2], nm[3]);
            mo4[1] = make_float4(nm[4], nm[5], nm[6], nm[7]);
            mo4[2] = make_float4(nm[8], nm[9], nm[10], nm[11]);
            mo4[3] = make_float4(nm[12], nm[13], nm[14], nm[15]);
        }
    }

    // ---- 1 point per thread, unroll-4 over k for ILP ----
    const int p = tile * LTILEP + tid;
    float fr[NC];
    #pragma unroll
    for (int c = 0; c < NC; ++c)
        fr[c] = feat[((size_t)b * NC + c) * NP + p];
    float f2 = 0.f;
    #pragma unroll
    for (int c = 0; c < NC; ++c) f2 += fr[c] * fr[c];
    __syncthreads();

    float best = 3.4e38f;
    int bi = 0;
    const float4* smv = reinterpret_cast<const float4*>(&sm[0][0]);
    #pragma unroll 4
    for (int k = 0; k < NK; ++k) {
        float4 m0 = smv[k * 4 + 0], m1 = smv[k * 4 + 1];
        float4 m2v = smv[k * 4 + 2], m3 = smv[k * 4 + 3];
        float mm[NC] = {m0.x,m0.y,m0.z,m0.w, m1.x,m1.y,m1.z,m1.w,
                        m2v.x,m2v.y,m2v.z,m2v.w, m3.x,m3.y,m3.z,m3.w};
        float m2 = sm2[k];
        float dot = 0.f;
        #pragma unroll
        for (int c = 0; c < NC; ++c) dot = fmaf(fr[c], mm[c], dot);
        float d2 = (f2 - 2.f * dot) + m2;
        if (d2 < best) { best = d2; bi = k; }
    }

    out[(size_t)b * NP + p] = (best < BW2) ? (float)(bi + 1) : 0.f;
}

extern "C" void kernel_launch(void* const* d_in, const int* in_sizes, int n_in,
                              void* d_out, int out_size, void* d_ws, size_t ws_size,
                              hipStream_t stream) {
    const float* feat = (const float*)d_in[0];
    const int* seed = (const int*)d_in[1];
    float* out = (float*)d_out;
    float* ws = (float*)d_ws;

    ms_init<<<84, 256, 0, stream>>>(feat, seed, ws);
    for (int i = 0; i < NITER; ++i) {
        ms_accum<<<NB * NTILES * KS, TPB, 0, stream>>>(
            feat, ws, (i + 2) % 3, i % 3, (i + 1) % 3, (i + 1) & 1, i & 1);
    }
    ms_label<<<NB * LNTILES, TPB, 0, stream>>>(feat, ws, out, (NITER + 2) % 3, (NITER + 1) & 1);
}